// Round 3
// baseline (1023.275 us; speedup 1.0000x reference)
//
#include <hip/hip_runtime.h>
#include <math.h>

#define NN   100000
#define HH   128
#define INF_ 35
#define GG   1000

static __device__ __forceinline__ float silu_f(float x){ return x / (1.f + __expf(-x)); }
#define BN_INV 0.9999950000374997f  /* 1/sqrt(1+1e-5) */

// ---------------- CSR build ----------------
__global__ void k_count(const int* __restrict__ col, int E, int* __restrict__ deg){
    int e = blockIdx.x*256 + threadIdx.x;
    if (e < E) atomicAdd(&deg[col[e]], 1);
}

__global__ void k_scan1(const int* __restrict__ deg, int n, int* __restrict__ off, int* __restrict__ bsum){
    __shared__ int s[256];
    int tid = threadIdx.x; int i = blockIdx.x*256 + tid;
    int v = (i<n)? deg[i] : 0;
    s[tid] = v; __syncthreads();
    for (int ofs=1; ofs<256; ofs<<=1){
        int t = (tid>=ofs)? s[tid-ofs] : 0;
        __syncthreads(); s[tid] += t; __syncthreads();
    }
    if (i<n) off[i] = s[tid] - v;
    if (tid==255) bsum[blockIdx.x] = s[255];
}

__global__ void k_scan2(int* __restrict__ bsum, int nb){
    __shared__ int s[512];
    int tid = threadIdx.x;
    int v = (tid<nb)? bsum[tid] : 0;
    s[tid] = v; __syncthreads();
    for (int ofs=1; ofs<512; ofs<<=1){
        int t = (tid>=ofs)? s[tid-ofs] : 0;
        __syncthreads(); s[tid] += t; __syncthreads();
    }
    if (tid<nb) bsum[tid] = s[tid] - v;
}

__global__ void k_scan3(int* __restrict__ off, const int* __restrict__ bsum, int n, int E){
    int i = blockIdx.x*256 + threadIdx.x;
    if (i<n) off[i] += bsum[i>>8];
    if (i==0) off[n] = E;
}

// fill CSR records: {rb[0..8], src, d, pad} = 12 dwords (48B, float4-aligned)
__global__ void k_fill(const int* __restrict__ row, const int* __restrict__ colv, int E,
                       const float* __restrict__ pos,
                       const int* __restrict__ off, int* __restrict__ cur,
                       float4* __restrict__ rec){
    int e = blockIdx.x*256 + threadIdx.x;
    if (e >= E) return;
    int c = colv[e], r = row[e];
    int slot = atomicAdd(&cur[c], 1);
    int p = off[c] + slot;
    float dx = pos[r*3+0]-pos[c*3+0];
    float dy = pos[r*3+1]-pos[c*3+1];
    float dz = pos[r*3+2]-pos[c*3+2];
    float d  = sqrtf(dx*dx + dy*dy + dz*dz);
    float rb[9];
    #pragma unroll
    for (int k=0;k<9;k++){
        float t = (d - 0.75f*(float)k) * 1.5f;   // (d-mu)/sigma, sigma=2/3
        rb[k] = __expf(-t*t);
    }
    rec[(size_t)p*3+0] = make_float4(rb[0],rb[1],rb[2],rb[3]);
    rec[(size_t)p*3+1] = make_float4(rb[4],rb[5],rb[6],rb[7]);
    rec[(size_t)p*3+2] = make_float4(rb[8], __int_as_float(r), d, 0.f);
}

// ---------------- input: h = silu(x @ W_in + b) ----------------
#define NT_IN (NN/16)
__global__ __launch_bounds__(256) void k_input(const float* __restrict__ x, const float* __restrict__ W,
                        const float* __restrict__ b, float* __restrict__ h){
    __shared__ __align__(16) float xs[16][36];
    int tx = threadIdx.x;
    int c = tx & 127, g = tx >> 7;
    float4 wv[9];
    {
        float* wf = (float*)wv;
        #pragma unroll
        for (int k=0;k<INF_;k++) wf[k] = W[k*HH + c];
        wf[35] = 0.f;
    }
    float bc = b[c];
    for (int tile = blockIdx.x; tile < NT_IN; tile += gridDim.x){
        int r0 = tile*16;
        for (int i = tx; i < 16*INF_; i += 256){
            int rr = i/INF_, kk = i - rr*INF_;
            xs[rr][kk] = x[(size_t)(r0+rr)*INF_ + kk];
        }
        if (tx < 16) xs[tx][35] = 0.f;
        __syncthreads();
        float acc[8];
        #pragma unroll
        for (int j=0;j<8;j++) acc[j] = bc;
        #pragma unroll
        for (int kk=0;kk<9;kk++){
            float4 w4 = wv[kk];
            #pragma unroll
            for (int j=0;j<8;j++){
                float4 xv = *(const float4*)(&xs[g*8+j][kk*4]);
                acc[j] += xv.x*w4.x + xv.y*w4.y + xv.z*w4.z + xv.w*w4.w;
            }
        }
        #pragma unroll
        for (int j=0;j<8;j++){
            int gr = r0 + g*8 + j;
            h[(size_t)gr*HH + c] = silu_f(acc[j]);
        }
        __syncthreads();
    }
}

// ---------------- gather: agg[v] = h[v] + sum_in h[src]*silu(rb@cW+cB) ----------------
// 1 wave per node, float2 columns, precomputed RBF records, 2-edge unroll.
__global__ __launch_bounds__(256) void k_gather(const float* __restrict__ h, const int* __restrict__ off,
                         const float4* __restrict__ rec,
                         const float* __restrict__ cW, const float* __restrict__ cB,
                         float* __restrict__ agg, int n){
    int node = blockIdx.x*4 + (threadIdx.x>>6);
    if (node >= n) return;
    int c = (threadIdx.x & 63)*2;
    float w0[9], w1[9];
    #pragma unroll
    for (int k=0;k<9;k++){
        float2 t = *(const float2*)(cW + k*HH + c);
        w0[k]=t.x; w1[k]=t.y;
    }
    float2 cb = *(const float2*)(cB + c);
    float2 acc = *(const float2*)(h + (size_t)node*HH + c);
    int lo = off[node], hi = off[node+1];
    int p = lo;
    for (; p+2<=hi; p+=2){
        float4 a0 = rec[(size_t)p*3+0];
        float4 a1 = rec[(size_t)p*3+1];
        float4 a2 = rec[(size_t)p*3+2];
        float4 b0 = rec[(size_t)p*3+3];
        float4 b1 = rec[(size_t)p*3+4];
        float4 b2 = rec[(size_t)p*3+5];
        int sA = __float_as_int(a2.y);
        int sB = __float_as_int(b2.y);
        float2 hvA = *(const float2*)(h + (size_t)sA*HH + c);
        float2 hvB = *(const float2*)(h + (size_t)sB*HH + c);
        float qA0 = cb.x, qA1 = cb.y, qB0 = cb.x, qB1 = cb.y;
        qA0 += a0.x*w0[0]; qA1 += a0.x*w1[0];
        qA0 += a0.y*w0[1]; qA1 += a0.y*w1[1];
        qA0 += a0.z*w0[2]; qA1 += a0.z*w1[2];
        qA0 += a0.w*w0[3]; qA1 += a0.w*w1[3];
        qA0 += a1.x*w0[4]; qA1 += a1.x*w1[4];
        qA0 += a1.y*w0[5]; qA1 += a1.y*w1[5];
        qA0 += a1.z*w0[6]; qA1 += a1.z*w1[6];
        qA0 += a1.w*w0[7]; qA1 += a1.w*w1[7];
        qA0 += a2.x*w0[8]; qA1 += a2.x*w1[8];
        qB0 += b0.x*w0[0]; qB1 += b0.x*w1[0];
        qB0 += b0.y*w0[1]; qB1 += b0.y*w1[1];
        qB0 += b0.z*w0[2]; qB1 += b0.z*w1[2];
        qB0 += b0.w*w0[3]; qB1 += b0.w*w1[3];
        qB0 += b1.x*w0[4]; qB1 += b1.x*w1[4];
        qB0 += b1.y*w0[5]; qB1 += b1.y*w1[5];
        qB0 += b1.z*w0[6]; qB1 += b1.z*w1[6];
        qB0 += b1.w*w0[7]; qB1 += b1.w*w1[7];
        qB0 += b2.x*w0[8]; qB1 += b2.x*w1[8];
        acc.x += hvA.x * silu_f(qA0);
        acc.y += hvA.y * silu_f(qA1);
        acc.x += hvB.x * silu_f(qB0);
        acc.y += hvB.y * silu_f(qB1);
    }
    if (p < hi){
        float4 a0 = rec[(size_t)p*3+0];
        float4 a1 = rec[(size_t)p*3+1];
        float4 a2 = rec[(size_t)p*3+2];
        int sA = __float_as_int(a2.y);
        float2 hvA = *(const float2*)(h + (size_t)sA*HH + c);
        float qA0 = cb.x, qA1 = cb.y;
        qA0 += a0.x*w0[0]; qA1 += a0.x*w1[0];
        qA0 += a0.y*w0[1]; qA1 += a0.y*w1[1];
        qA0 += a0.z*w0[2]; qA1 += a0.z*w1[2];
        qA0 += a0.w*w0[3]; qA1 += a0.w*w1[3];
        qA0 += a1.x*w0[4]; qA1 += a1.x*w1[4];
        qA0 += a1.y*w0[5]; qA1 += a1.y*w1[5];
        qA0 += a1.z*w0[6]; qA1 += a1.z*w1[6];
        qA0 += a1.w*w0[7]; qA1 += a1.w*w1[7];
        qA0 += a2.x*w0[8]; qA1 += a2.x*w1[8];
        acc.x += hvA.x * silu_f(qA0);
        acc.y += hvA.y * silu_f(qA1);
    }
    *(float2*)(agg + (size_t)node*HH + c) = acc;
}

// ---------------- fused dual-branch node GEMM + leaky + BN + add ----------------
#define BM  64
#define BKF 16
#define ASTR 68
__global__ __launch_bounds__(256) void k_gemm2(
        const float* __restrict__ A1, const float* __restrict__ A2,
        const float* __restrict__ B1, const float* __restrict__ B2,
        const float* __restrict__ b1, const float* __restrict__ b2,
        const float* __restrict__ g1, const float* __restrict__ g2,
        const float* __restrict__ e1, const float* __restrict__ e2,
        float* __restrict__ C, int n){
    __shared__ __align__(16) float As1[BKF][ASTR];
    __shared__ __align__(16) float As2[BKF][ASTR];
    __shared__ __align__(16) float Bs1[BKF][HH];
    __shared__ __align__(16) float Bs2[BKF][HH];
    int tx = threadIdx.x;
    int rb = blockIdx.x*BM;
    int c0 = (tx&31)*4, r0 = (tx>>5)*8;
    float acc1[8][4], acc2[8][4];
    #pragma unroll
    for (int j=0;j<8;j++)
        #pragma unroll
        for (int q=0;q<4;q++){ acc1[j][q]=0.f; acc2[j][q]=0.f; }

    int arow = tx>>2, akk = (tx&3)*4;
    int gra = rb + arow;

    for (int kt=0; kt<HH; kt+=BKF){
        float4 v1 = make_float4(0.f,0.f,0.f,0.f);
        float4 v2 = make_float4(0.f,0.f,0.f,0.f);
        if (gra < n){
            v1 = *(const float4*)(A1 + (size_t)gra*HH + kt + akk);
            v2 = *(const float4*)(A2 + (size_t)gra*HH + kt + akk);
        }
        As1[akk+0][arow]=v1.x; As1[akk+1][arow]=v1.y; As1[akk+2][arow]=v1.z; As1[akk+3][arow]=v1.w;
        As2[akk+0][arow]=v2.x; As2[akk+1][arow]=v2.y; As2[akk+2][arow]=v2.z; As2[akk+3][arow]=v2.w;
        #pragma unroll
        for (int it=0; it<2; it++){
            int q = tx + it*256;
            int kr = q>>5, cc = (q&31)*4;
            *(float4*)(&Bs1[kr][cc]) = *(const float4*)(B1 + (size_t)(kt+kr)*HH + cc);
            *(float4*)(&Bs2[kr][cc]) = *(const float4*)(B2 + (size_t)(kt+kr)*HH + cc);
        }
        __syncthreads();
        #pragma unroll
        for (int k=0;k<BKF;k++){
            float4 bv1 = *(const float4*)(&Bs1[k][c0]);
            float4 a1l = *(const float4*)(&As1[k][r0]);
            float4 a1h = *(const float4*)(&As1[k][r0+4]);
            float ar1[8] = {a1l.x,a1l.y,a1l.z,a1l.w,a1h.x,a1h.y,a1h.z,a1h.w};
            #pragma unroll
            for (int j=0;j<8;j++){
                acc1[j][0] += ar1[j]*bv1.x;
                acc1[j][1] += ar1[j]*bv1.y;
                acc1[j][2] += ar1[j]*bv1.z;
                acc1[j][3] += ar1[j]*bv1.w;
            }
            float4 bv2 = *(const float4*)(&Bs2[k][c0]);
            float4 a2l = *(const float4*)(&As2[k][r0]);
            float4 a2h = *(const float4*)(&As2[k][r0+4]);
            float ar2[8] = {a2l.x,a2l.y,a2l.z,a2l.w,a2h.x,a2h.y,a2h.z,a2h.w};
            #pragma unroll
            for (int j=0;j<8;j++){
                acc2[j][0] += ar2[j]*bv2.x;
                acc2[j][1] += ar2[j]*bv2.y;
                acc2[j][2] += ar2[j]*bv2.z;
                acc2[j][3] += ar2[j]*bv2.w;
            }
        }
        __syncthreads();
    }

    float4 bi1 = *(const float4*)(b1 + c0);
    float4 ga1 = *(const float4*)(g1 + c0);
    float4 be1 = *(const float4*)(e1 + c0);
    float4 bi2 = *(const float4*)(b2 + c0);
    float4 ga2 = *(const float4*)(g2 + c0);
    float4 be2 = *(const float4*)(e2 + c0);
    #pragma unroll
    for (int j=0;j<8;j++){
        int gr = rb + r0 + j;
        if (gr < n){
            float x0,x1,x2,x3,y0,y1,y2,y3;
            x0 = acc1[j][0]+bi1.x; x1 = acc1[j][1]+bi1.y; x2 = acc1[j][2]+bi1.z; x3 = acc1[j][3]+bi1.w;
            x0 = (x0>=0.f)? x0 : 0.01f*x0;  x1 = (x1>=0.f)? x1 : 0.01f*x1;
            x2 = (x2>=0.f)? x2 : 0.01f*x2;  x3 = (x3>=0.f)? x3 : 0.01f*x3;
            y0 = acc2[j][0]+bi2.x; y1 = acc2[j][1]+bi2.y; y2 = acc2[j][2]+bi2.z; y3 = acc2[j][3]+bi2.w;
            y0 = (y0>=0.f)? y0 : 0.01f*y0;  y1 = (y1>=0.f)? y1 : 0.01f*y1;
            y2 = (y2>=0.f)? y2 : 0.01f*y2;  y3 = (y3>=0.f)? y3 : 0.01f*y3;
            float4 o;
            o.x = (ga1.x*x0 + ga2.x*y0)*BN_INV + be1.x + be2.x;
            o.y = (ga1.y*x1 + ga2.y*y1)*BN_INV + be1.y + be2.y;
            o.z = (ga1.z*x2 + ga2.z*y2)*BN_INV + be1.z + be2.z;
            o.w = (ga1.w*x3 + ga2.w*y3)*BN_INV + be1.w + be2.w;
            *(float4*)(C + (size_t)gr*HH + c0) = o;
        }
    }
}

// ---------------- pool (batch is sorted) ----------------
static __device__ __forceinline__ int lower_bound_i(const int* __restrict__ a, int n, int key){
    int lo=0, hi=n;
    while (lo<hi){ int m=(lo+hi)>>1; if (a[m]<key) lo=m+1; else hi=m; }
    return lo;
}
__global__ void k_pool(const float* __restrict__ h, const int* __restrict__ batch,
                       float* __restrict__ hg, int n){
    int g = blockIdx.x, c = threadIdx.x;
    int lo = lower_bound_i(batch, n, g);
    int hi = lower_bound_i(batch, n, g+1);
    float acc = 0.f;
    for (int v=lo; v<hi; v++) acc += h[(size_t)v*HH + c];
    hg[(size_t)g*HH + c] = acc;
}

// ---------------- fused FC x3 + head ----------------
__global__ void k_fc(const float* __restrict__ hg, const float* __restrict__ fcW,
                     const float* __restrict__ fcB, const float* __restrict__ fbg,
                     const float* __restrict__ fbb, const float* __restrict__ outW,
                     const float* __restrict__ outB, float* __restrict__ out){
    __shared__ float row[HH];
    __shared__ float red[2];
    int g = blockIdx.x, c = threadIdx.x;
    float v = hg[(size_t)g*HH + c];
    for (int l=0;l<3;l++){
        row[c] = v; __syncthreads();
        float acc = fcB[l*HH + c];
        const float* W = fcW + (size_t)l*HH*HH;
        #pragma unroll 8
        for (int k=0;k<HH;k++) acc += row[k]*W[k*HH + c];
        acc = (acc>=0.f)? acc : 0.01f*acc;
        v = fbg[l*HH+c]*acc*BN_INV + fbb[l*HH+c];
        __syncthreads();
    }
    float t = v * outW[c];
    #pragma unroll
    for (int o=32;o>0;o>>=1) t += __shfl_down(t, o, 64);
    if ((c&63)==0) red[c>>6] = t;
    __syncthreads();
    if (c==0) out[g] = red[0] + red[1] + outB[0];
}

extern "C" void kernel_launch(void* const* d_in, const int* in_sizes, int n_in,
                              void* d_out, int out_size, void* d_ws, size_t ws_size,
                              hipStream_t stream){
    const float* x      = (const float*)d_in[0];
    const float* pos    = (const float*)d_in[1];
    const float* W_in   = (const float*)d_in[2];
    const float* b_in   = (const float*)d_in[3];
    const float* coordW = (const float*)d_in[4];
    const float* coordB = (const float*)d_in[5];
    const float* nodeW  = (const float*)d_in[6];
    const float* nodeB  = (const float*)d_in[7];
    const float* bnG    = (const float*)d_in[8];
    const float* bnB    = (const float*)d_in[9];
    const float* fcW    = (const float*)d_in[10];
    const float* fcB    = (const float*)d_in[11];
    const float* fcBnG  = (const float*)d_in[12];
    const float* fcBnB  = (const float*)d_in[13];
    const float* outW   = (const float*)d_in[14];
    const float* outB   = (const float*)d_in[15];
    const int* ei1      = (const int*)d_in[16];
    const int* ei2      = (const int*)d_in[17];
    const int* batch    = (const int*)d_in[18];
    const int E1 = in_sizes[16]/2, E2 = in_sizes[17]/2;
    const int n = NN;

    char* w = (char*)d_ws;
    size_t o = 0;
    auto alloc = [&](size_t bytes)->void*{
        void* r = w + o;
        o += (bytes + 255) & ~(size_t)255;
        return r;
    };
    float*  h    = (float*)alloc((size_t)n*HH*4);
    float*  h2   = (float*)alloc((size_t)n*HH*4);
    float*  agg  = (float*)alloc((size_t)n*HH*4);
    int*    off1 = (int*)alloc((size_t)(n+1)*4);
    int*    off2 = (int*)alloc((size_t)(n+1)*4);
    float4* rec1 = (float4*)alloc((size_t)E1*48);
    float4* rec2 = (float4*)alloc((size_t)E2*48);
    int*    tmp  = (int*)alloc((size_t)n*4);
    int*    bsum = (int*)alloc(512*4);
    float*  hg   = (float*)alloc((size_t)GG*HH*4);
    (void)ws_size; (void)n_in; (void)out_size;

    int nb = (n+255)/256;

    // CSR intra
    hipMemsetAsync(tmp, 0, (size_t)n*4, stream);
    k_count<<<(E1+255)/256,256,0,stream>>>(ei1+E1, E1, tmp);
    k_scan1<<<nb,256,0,stream>>>(tmp, n, off1, bsum);
    k_scan2<<<1,512,0,stream>>>(bsum, nb);
    k_scan3<<<nb,256,0,stream>>>(off1, bsum, n, E1);
    hipMemsetAsync(tmp, 0, (size_t)n*4, stream);
    k_fill<<<(E1+255)/256,256,0,stream>>>(ei1, ei1+E1, E1, pos, off1, tmp, rec1);

    // CSR inter
    hipMemsetAsync(tmp, 0, (size_t)n*4, stream);
    k_count<<<(E2+255)/256,256,0,stream>>>(ei2+E2, E2, tmp);
    k_scan1<<<nb,256,0,stream>>>(tmp, n, off2, bsum);
    k_scan2<<<1,512,0,stream>>>(bsum, nb);
    k_scan3<<<nb,256,0,stream>>>(off2, bsum, n, E2);
    hipMemsetAsync(tmp, 0, (size_t)n*4, stream);
    k_fill<<<(E2+255)/256,256,0,stream>>>(ei2, ei2+E2, E2, pos, off2, tmp, rec2);

    // input projection
    k_input<<<2048,256,0,stream>>>(x, W_in, b_in, h);

    float* hcur = h;
    float* hoth = h2;
    for (int l=0; l<3; l++){
        int li0 = l*2, li1 = l*2+1;
        k_gather<<<(n+3)/4,256,0,stream>>>(hcur, off1, rec1,
            coordW + (size_t)li0*9*HH, coordB + (size_t)li0*HH, agg, n);
        k_gather<<<(n+3)/4,256,0,stream>>>(hcur, off2, rec2,
            coordW + (size_t)li1*9*HH, coordB + (size_t)li1*HH, hoth, n);
        k_gemm2<<<(n+BM-1)/BM,256,0,stream>>>(agg, hoth,
            nodeW + (size_t)li0*HH*HH, nodeW + (size_t)li1*HH*HH,
            nodeB + (size_t)li0*HH,  nodeB + (size_t)li1*HH,
            bnG   + (size_t)li0*HH,  bnG   + (size_t)li1*HH,
            bnB   + (size_t)li0*HH,  bnB   + (size_t)li1*HH,
            hoth, n);
        float* t = hcur; hcur = hoth; hoth = t;
    }

    k_pool<<<GG,128,0,stream>>>(hcur, batch, hg, n);
    k_fc<<<GG,128,0,stream>>>(hg, fcW, fcB, fcBnG, fcBnB, outW, outB, (float*)d_out);
}

// Round 4
// 803.037 us; speedup vs baseline: 1.2743x; 1.2743x over previous
//
#include <hip/hip_runtime.h>
#include <math.h>

#define NN   100000
#define HH   128
#define INF_ 35
#define GG   1000

static __device__ __forceinline__ float silu_f(float x){ return x / (1.f + __expf(-x)); }
#define BN_INV 0.9999950000374997f  /* 1/sqrt(1+1e-5) */

// ---------------- stacked CSR build (both graphs, dst' = dst + n*branch) ----------------
__global__ void k_count(const int* __restrict__ ei1, const int* __restrict__ ei2,
                        int E1, int E2, int n, int* __restrict__ deg){
    int e = blockIdx.x*256 + threadIdx.x;
    int ET = E1 + E2;
    if (e >= ET) return;
    int c;
    if (e < E1) c = ei1[E1 + e];
    else        c = n + ei2[E2 + (e - E1)];
    atomicAdd(&deg[c], 1);
}

__global__ void k_scan1(const int* __restrict__ deg, int n2, int* __restrict__ off, int* __restrict__ bsum){
    __shared__ int s[256];
    int tid = threadIdx.x; int i = blockIdx.x*256 + tid;
    int v = (i<n2)? deg[i] : 0;
    s[tid] = v; __syncthreads();
    for (int ofs=1; ofs<256; ofs<<=1){
        int t = (tid>=ofs)? s[tid-ofs] : 0;
        __syncthreads(); s[tid] += t; __syncthreads();
    }
    if (i<n2) off[i] = s[tid] - v;
    if (tid==255) bsum[blockIdx.x] = s[255];
}

__global__ void k_scan2(int* __restrict__ bsum, int nb){
    __shared__ int s[1024];
    int tid = threadIdx.x;
    int v = (tid<nb)? bsum[tid] : 0;
    s[tid] = v; __syncthreads();
    for (int ofs=1; ofs<1024; ofs<<=1){
        int t = (tid>=ofs)? s[tid-ofs] : 0;
        __syncthreads(); s[tid] += t; __syncthreads();
    }
    if (tid<nb) bsum[tid] = s[tid] - v;
}

__global__ void k_scan3(int* __restrict__ off, const int* __restrict__ bsum, int n2, int ET){
    int i = blockIdx.x*256 + threadIdx.x;
    if (i<n2) off[i] += bsum[i>>8];
    if (i==0) off[n2] = ET;
}

// fill stacked CSR records: {rb[0..8], src, d, pad} = 48B
__global__ void k_fill(const int* __restrict__ ei1, const int* __restrict__ ei2,
                       int E1, int E2, int n, const float* __restrict__ pos,
                       const int* __restrict__ off, int* __restrict__ cur,
                       float4* __restrict__ rec){
    int e = blockIdx.x*256 + threadIdx.x;
    int ET = E1 + E2;
    if (e >= ET) return;
    int r, creal, cslot;
    if (e < E1){ r = ei1[e];        creal = ei1[E1 + e];        cslot = creal; }
    else       { int ee = e - E1; r = ei2[ee]; creal = ei2[E2 + ee]; cslot = n + creal; }
    int slot = atomicAdd(&cur[cslot], 1);
    int p = off[cslot] + slot;
    float dx = pos[r*3+0]-pos[creal*3+0];
    float dy = pos[r*3+1]-pos[creal*3+1];
    float dz = pos[r*3+2]-pos[creal*3+2];
    float d  = sqrtf(dx*dx + dy*dy + dz*dz);
    float rb[9];
    #pragma unroll
    for (int k=0;k<9;k++){
        float t = (d - 0.75f*(float)k) * 1.5f;
        rb[k] = __expf(-t*t);
    }
    rec[(size_t)p*3+0] = make_float4(rb[0],rb[1],rb[2],rb[3]);
    rec[(size_t)p*3+1] = make_float4(rb[4],rb[5],rb[6],rb[7]);
    rec[(size_t)p*3+2] = make_float4(rb[8], __int_as_float(r), d, 0.f);
}

// ---------------- input: h = silu(x @ W_in + b) ----------------
#define NT_IN (NN/16)
__global__ __launch_bounds__(256) void k_input(const float* __restrict__ x, const float* __restrict__ W,
                        const float* __restrict__ b, float* __restrict__ h){
    __shared__ __align__(16) float xs[16][36];
    int tx = threadIdx.x;
    int c = tx & 127, g = tx >> 7;
    float4 wv[9];
    {
        float* wf = (float*)wv;
        #pragma unroll
        for (int k=0;k<INF_;k++) wf[k] = W[k*HH + c];
        wf[35] = 0.f;
    }
    float bc = b[c];
    for (int tile = blockIdx.x; tile < NT_IN; tile += gridDim.x){
        int r0 = tile*16;
        for (int i = tx; i < 16*INF_; i += 256){
            int rr = i/INF_, kk = i - rr*INF_;
            xs[rr][kk] = x[(size_t)(r0+rr)*INF_ + kk];
        }
        if (tx < 16) xs[tx][35] = 0.f;
        __syncthreads();
        float acc[8];
        #pragma unroll
        for (int j=0;j<8;j++) acc[j] = bc;
        #pragma unroll
        for (int kk=0;kk<9;kk++){
            float4 w4 = wv[kk];
            #pragma unroll
            for (int j=0;j<8;j++){
                float4 xv = *(const float4*)(&xs[g*8+j][kk*4]);
                acc[j] += xv.x*w4.x + xv.y*w4.y + xv.z*w4.z + xv.w*w4.w;
            }
        }
        #pragma unroll
        for (int j=0;j<8;j++){
            int gr = r0 + g*8 + j;
            h[(size_t)gr*HH + c] = silu_f(acc[j]);
        }
        __syncthreads();
    }
}

// ---------------- merged dual-branch gather ----------------
// blocks [0, nblk1): branch0 -> agg1 ; [nblk1, 2*nblk1): branch1 -> agg2.
// 1 wave per node; rec bounds made wave-uniform via readfirstlane so rec loads scalarize.
__global__ __launch_bounds__(256) void k_gather(const float* __restrict__ h,
        const int* __restrict__ off, const float4* __restrict__ rec,
        const float* __restrict__ cWl, const float* __restrict__ cBl,
        float* __restrict__ agg1, float* __restrict__ agg2, int n, int nblk1){
    int b = blockIdx.x;
    int br = (b >= nblk1) ? 1 : 0;
    int node = (br ? b - nblk1 : b)*4 + (threadIdx.x>>6);
    if (node >= n) return;
    int c = (threadIdx.x & 63)*2;
    const float* cW = cWl + br*(9*HH);
    const float* cB = cBl + br*HH;
    float* aggp = br ? agg2 : agg1;

    float w0[9], w1[9];
    #pragma unroll
    for (int k=0;k<9;k++){
        float2 t = *(const float2*)(cW + k*HH + c);
        w0[k]=t.x; w1[k]=t.y;
    }
    float2 cb = *(const float2*)(cB + c);
    float2 acc = *(const float2*)(h + (size_t)node*HH + c);

    int slot = node + br*n;
    int lo = off[slot], hi = off[slot+1];
    lo = __builtin_amdgcn_readfirstlane(lo);
    hi = __builtin_amdgcn_readfirstlane(hi);

    const float4* rp = rec + (size_t)lo*3;
    int p = lo;
    for (; p+2<=hi; p+=2, rp+=6){
        float4 a0 = rp[0];
        float4 a1 = rp[1];
        float4 a2 = rp[2];
        float4 b0 = rp[3];
        float4 b1 = rp[4];
        float4 b2 = rp[5];
        int sA = __float_as_int(a2.y);
        int sB = __float_as_int(b2.y);
        float2 hvA = *(const float2*)(h + (size_t)sA*HH + c);
        float2 hvB = *(const float2*)(h + (size_t)sB*HH + c);
        float qA0 = cb.x, qA1 = cb.y, qB0 = cb.x, qB1 = cb.y;
        qA0 += a0.x*w0[0]; qA1 += a0.x*w1[0];
        qA0 += a0.y*w0[1]; qA1 += a0.y*w1[1];
        qA0 += a0.z*w0[2]; qA1 += a0.z*w1[2];
        qA0 += a0.w*w0[3]; qA1 += a0.w*w1[3];
        qA0 += a1.x*w0[4]; qA1 += a1.x*w1[4];
        qA0 += a1.y*w0[5]; qA1 += a1.y*w1[5];
        qA0 += a1.z*w0[6]; qA1 += a1.z*w1[6];
        qA0 += a1.w*w0[7]; qA1 += a1.w*w1[7];
        qA0 += a2.x*w0[8]; qA1 += a2.x*w1[8];
        qB0 += b0.x*w0[0]; qB1 += b0.x*w1[0];
        qB0 += b0.y*w0[1]; qB1 += b0.y*w1[1];
        qB0 += b0.z*w0[2]; qB1 += b0.z*w1[2];
        qB0 += b0.w*w0[3]; qB1 += b0.w*w1[3];
        qB0 += b1.x*w0[4]; qB1 += b1.x*w1[4];
        qB0 += b1.y*w0[5]; qB1 += b1.y*w1[5];
        qB0 += b1.z*w0[6]; qB1 += b1.z*w1[6];
        qB0 += b1.w*w0[7]; qB1 += b1.w*w1[7];
        qB0 += b2.x*w0[8]; qB1 += b2.x*w1[8];
        acc.x += hvA.x * silu_f(qA0);
        acc.y += hvA.y * silu_f(qA1);
        acc.x += hvB.x * silu_f(qB0);
        acc.y += hvB.y * silu_f(qB1);
    }
    if (p < hi){
        float4 a0 = rp[0];
        float4 a1 = rp[1];
        float4 a2 = rp[2];
        int sA = __float_as_int(a2.y);
        float2 hvA = *(const float2*)(h + (size_t)sA*HH + c);
        float qA0 = cb.x, qA1 = cb.y;
        qA0 += a0.x*w0[0]; qA1 += a0.x*w1[0];
        qA0 += a0.y*w0[1]; qA1 += a0.y*w1[1];
        qA0 += a0.z*w0[2]; qA1 += a0.z*w1[2];
        qA0 += a0.w*w0[3]; qA1 += a0.w*w1[3];
        qA0 += a1.x*w0[4]; qA1 += a1.x*w1[4];
        qA0 += a1.y*w0[5]; qA1 += a1.y*w1[5];
        qA0 += a1.z*w0[6]; qA1 += a1.z*w1[6];
        qA0 += a1.w*w0[7]; qA1 += a1.w*w1[7];
        qA0 += a2.x*w0[8]; qA1 += a2.x*w1[8];
        acc.x += hvA.x * silu_f(qA0);
        acc.y += hvA.y * silu_f(qA1);
    }
    *(float2*)(aggp + (size_t)node*HH + c) = acc;
}

// ---------------- fused dual-branch node GEMM + leaky + BN + add ----------------
#define BM  64
#define BKF 16
#define ASTR 68
__global__ __launch_bounds__(256) void k_gemm2(
        const float* __restrict__ A1, const float* __restrict__ A2,
        const float* __restrict__ B1, const float* __restrict__ B2,
        const float* __restrict__ b1, const float* __restrict__ b2,
        const float* __restrict__ g1, const float* __restrict__ g2,
        const float* __restrict__ e1, const float* __restrict__ e2,
        float* __restrict__ C, int n){
    __shared__ __align__(16) float As1[BKF][ASTR];
    __shared__ __align__(16) float As2[BKF][ASTR];
    __shared__ __align__(16) float Bs1[BKF][HH];
    __shared__ __align__(16) float Bs2[BKF][HH];
    int tx = threadIdx.x;
    int rb = blockIdx.x*BM;
    int c0 = (tx&31)*4, r0 = (tx>>5)*8;
    float acc1[8][4], acc2[8][4];
    #pragma unroll
    for (int j=0;j<8;j++)
        #pragma unroll
        for (int q=0;q<4;q++){ acc1[j][q]=0.f; acc2[j][q]=0.f; }

    int arow = tx>>2, akk = (tx&3)*4;
    int gra = rb + arow;

    for (int kt=0; kt<HH; kt+=BKF){
        float4 v1 = make_float4(0.f,0.f,0.f,0.f);
        float4 v2 = make_float4(0.f,0.f,0.f,0.f);
        if (gra < n){
            v1 = *(const float4*)(A1 + (size_t)gra*HH + kt + akk);
            v2 = *(const float4*)(A2 + (size_t)gra*HH + kt + akk);
        }
        As1[akk+0][arow]=v1.x; As1[akk+1][arow]=v1.y; As1[akk+2][arow]=v1.z; As1[akk+3][arow]=v1.w;
        As2[akk+0][arow]=v2.x; As2[akk+1][arow]=v2.y; As2[akk+2][arow]=v2.z; As2[akk+3][arow]=v2.w;
        #pragma unroll
        for (int it=0; it<2; it++){
            int q = tx + it*256;
            int kr = q>>5, cc = (q&31)*4;
            *(float4*)(&Bs1[kr][cc]) = *(const float4*)(B1 + (size_t)(kt+kr)*HH + cc);
            *(float4*)(&Bs2[kr][cc]) = *(const float4*)(B2 + (size_t)(kt+kr)*HH + cc);
        }
        __syncthreads();
        #pragma unroll
        for (int k=0;k<BKF;k++){
            float4 bv1 = *(const float4*)(&Bs1[k][c0]);
            float4 a1l = *(const float4*)(&As1[k][r0]);
            float4 a1h = *(const float4*)(&As1[k][r0+4]);
            float ar1[8] = {a1l.x,a1l.y,a1l.z,a1l.w,a1h.x,a1h.y,a1h.z,a1h.w};
            #pragma unroll
            for (int j=0;j<8;j++){
                acc1[j][0] += ar1[j]*bv1.x;
                acc1[j][1] += ar1[j]*bv1.y;
                acc1[j][2] += ar1[j]*bv1.z;
                acc1[j][3] += ar1[j]*bv1.w;
            }
            float4 bv2 = *(const float4*)(&Bs2[k][c0]);
            float4 a2l = *(const float4*)(&As2[k][r0]);
            float4 a2h = *(const float4*)(&As2[k][r0+4]);
            float ar2[8] = {a2l.x,a2l.y,a2l.z,a2l.w,a2h.x,a2h.y,a2h.z,a2h.w};
            #pragma unroll
            for (int j=0;j<8;j++){
                acc2[j][0] += ar2[j]*bv2.x;
                acc2[j][1] += ar2[j]*bv2.y;
                acc2[j][2] += ar2[j]*bv2.z;
                acc2[j][3] += ar2[j]*bv2.w;
            }
        }
        __syncthreads();
    }

    float4 bi1 = *(const float4*)(b1 + c0);
    float4 ga1 = *(const float4*)(g1 + c0);
    float4 be1 = *(const float4*)(e1 + c0);
    float4 bi2 = *(const float4*)(b2 + c0);
    float4 ga2 = *(const float4*)(g2 + c0);
    float4 be2 = *(const float4*)(e2 + c0);
    #pragma unroll
    for (int j=0;j<8;j++){
        int gr = rb + r0 + j;
        if (gr < n){
            float x0,x1,x2,x3,y0,y1,y2,y3;
            x0 = acc1[j][0]+bi1.x; x1 = acc1[j][1]+bi1.y; x2 = acc1[j][2]+bi1.z; x3 = acc1[j][3]+bi1.w;
            x0 = (x0>=0.f)? x0 : 0.01f*x0;  x1 = (x1>=0.f)? x1 : 0.01f*x1;
            x2 = (x2>=0.f)? x2 : 0.01f*x2;  x3 = (x3>=0.f)? x3 : 0.01f*x3;
            y0 = acc2[j][0]+bi2.x; y1 = acc2[j][1]+bi2.y; y2 = acc2[j][2]+bi2.z; y3 = acc2[j][3]+bi2.w;
            y0 = (y0>=0.f)? y0 : 0.01f*y0;  y1 = (y1>=0.f)? y1 : 0.01f*y1;
            y2 = (y2>=0.f)? y2 : 0.01f*y2;  y3 = (y3>=0.f)? y3 : 0.01f*y3;
            float4 o;
            o.x = (ga1.x*x0 + ga2.x*y0)*BN_INV + be1.x + be2.x;
            o.y = (ga1.y*x1 + ga2.y*y1)*BN_INV + be1.y + be2.y;
            o.z = (ga1.z*x2 + ga2.z*y2)*BN_INV + be1.z + be2.z;
            o.w = (ga1.w*x3 + ga2.w*y3)*BN_INV + be1.w + be2.w;
            *(float4*)(C + (size_t)gr*HH + c0) = o;
        }
    }
}

// ---------------- fused pool + FC x3 + head ----------------
static __device__ __forceinline__ int lower_bound_i(const int* __restrict__ a, int n, int key){
    int lo=0, hi=n;
    while (lo<hi){ int m=(lo+hi)>>1; if (a[m]<key) lo=m+1; else hi=m; }
    return lo;
}
__global__ void k_poolfc(const float* __restrict__ h, const int* __restrict__ batch,
                     const float* __restrict__ fcW, const float* __restrict__ fcB,
                     const float* __restrict__ fbg, const float* __restrict__ fbb,
                     const float* __restrict__ outW, const float* __restrict__ outB,
                     float* __restrict__ out, int n){
    __shared__ float row[HH];
    __shared__ float red[2];
    int g = blockIdx.x, c = threadIdx.x;
    int lo = lower_bound_i(batch, n, g);
    int hi = lower_bound_i(batch, n, g+1);
    float v = 0.f;
    for (int r=lo; r<hi; r++) v += h[(size_t)r*HH + c];
    for (int l=0;l<3;l++){
        row[c] = v; __syncthreads();
        float acc = fcB[l*HH + c];
        const float* W = fcW + (size_t)l*HH*HH;
        #pragma unroll 8
        for (int k=0;k<HH;k++) acc += row[k]*W[k*HH + c];
        acc = (acc>=0.f)? acc : 0.01f*acc;
        v = fbg[l*HH+c]*acc*BN_INV + fbb[l*HH+c];
        __syncthreads();
    }
    float t = v * outW[c];
    #pragma unroll
    for (int o=32;o>0;o>>=1) t += __shfl_down(t, o, 64);
    if ((c&63)==0) red[c>>6] = t;
    __syncthreads();
    if (c==0) out[g] = red[0] + red[1] + outB[0];
}

extern "C" void kernel_launch(void* const* d_in, const int* in_sizes, int n_in,
                              void* d_out, int out_size, void* d_ws, size_t ws_size,
                              hipStream_t stream){
    const float* x      = (const float*)d_in[0];
    const float* pos    = (const float*)d_in[1];
    const float* W_in   = (const float*)d_in[2];
    const float* b_in   = (const float*)d_in[3];
    const float* coordW = (const float*)d_in[4];
    const float* coordB = (const float*)d_in[5];
    const float* nodeW  = (const float*)d_in[6];
    const float* nodeB  = (const float*)d_in[7];
    const float* bnG    = (const float*)d_in[8];
    const float* bnB    = (const float*)d_in[9];
    const float* fcW    = (const float*)d_in[10];
    const float* fcB    = (const float*)d_in[11];
    const float* fcBnG  = (const float*)d_in[12];
    const float* fcBnB  = (const float*)d_in[13];
    const float* outW   = (const float*)d_in[14];
    const float* outB   = (const float*)d_in[15];
    const int* ei1      = (const int*)d_in[16];
    const int* ei2      = (const int*)d_in[17];
    const int* batch    = (const int*)d_in[18];
    const int E1 = in_sizes[16]/2, E2 = in_sizes[17]/2;
    const int n = NN;
    const int n2 = 2*n;
    const int ET = E1 + E2;

    char* w = (char*)d_ws;
    size_t o = 0;
    auto alloc = [&](size_t bytes)->void*{
        void* r = w + o;
        o += (bytes + 255) & ~(size_t)255;
        return r;
    };
    float*  h    = (float*)alloc((size_t)n*HH*4);
    float*  h2   = (float*)alloc((size_t)n*HH*4);
    float*  agg  = (float*)alloc((size_t)n*HH*4);
    int*    off  = (int*)alloc((size_t)(n2+1)*4);
    int*    cnt  = (int*)alloc((size_t)n2*4);   // cnt and cur adjacent -> one memset
    int*    cur  = (int*)alloc((size_t)n2*4);
    float4* rec  = (float4*)alloc((size_t)ET*48);
    int*    bsum = (int*)alloc(1024*4);
    (void)ws_size; (void)n_in; (void)out_size;

    int nb2 = (n2+255)/256;

    hipMemsetAsync(cnt, 0, (size_t)2*n2*4, stream);
    k_count<<<(ET+255)/256,256,0,stream>>>(ei1, ei2, E1, E2, n, cnt);
    k_scan1<<<nb2,256,0,stream>>>(cnt, n2, off, bsum);
    k_scan2<<<1,1024,0,stream>>>(bsum, nb2);
    k_scan3<<<nb2,256,0,stream>>>(off, bsum, n2, ET);
    k_fill<<<(ET+255)/256,256,0,stream>>>(ei1, ei2, E1, E2, n, pos, off, cur, rec);

    k_input<<<2048,256,0,stream>>>(x, W_in, b_in, h);

    int nb4 = (n+3)/4;
    float* hcur = h;
    float* hoth = h2;
    for (int l=0; l<3; l++){
        int li0 = l*2, li1 = l*2+1;
        k_gather<<<2*nb4,256,0,stream>>>(hcur, off, rec,
            coordW + (size_t)li0*9*HH, coordB + (size_t)li0*HH, agg, hoth, n, nb4);
        k_gemm2<<<(n+BM-1)/BM,256,0,stream>>>(agg, hoth,
            nodeW + (size_t)li0*HH*HH, nodeW + (size_t)li1*HH*HH,
            nodeB + (size_t)li0*HH,  nodeB + (size_t)li1*HH,
            bnG   + (size_t)li0*HH,  bnG   + (size_t)li1*HH,
            bnB   + (size_t)li0*HH,  bnB   + (size_t)li1*HH,
            hoth, n);
        float* t = hcur; hcur = hoth; hoth = t;
    }

    k_poolfc<<<GG,128,0,stream>>>(hcur, batch, fcW, fcB, fcBnG, fcBnB, outW, outB, (float*)d_out, n);
}